// Round 3
// baseline (456.074 us; speedup 1.0000x reference)
//
#include <hip/hip_runtime.h>
#include <math.h>

#define B_ 64
#define T_ 2048
#define RNN_DIM 1024
#define EMB_DIM 512
#define ATT_DIM 128
#define N_FILT 32
#define KSIZE 31
#define PAD_ 15
#define TT 64           // t-tile for the fused kernel
#define NSLICE 32       // t-tiles per row
#define NPART 64        // 2 half-tile partials per tile

__device__ __forceinline__ float fast_tanh(float x) {
    // 1 - 2/(e^{2x}+1); exact at +-inf saturation, ~1e-7 abs err
    float e = __expf(2.0f * x);
    return 1.0f - 2.0f / (e + 1.0f);
}

// ---------------- Kernel A: pq[b,a] = sum_r query[b,r] * Wq[a,r] ----------
// grid (2, B): blockIdx.x picks 64 of the 128 outputs; 4-way K-split per
// output (rp = tid>>6) quarters the sequential-load latency chain.
__global__ __launch_bounds__(256) void k_pq(const float* __restrict__ query,
                                            const float* __restrict__ Wq,
                                            float* __restrict__ pq) {
    __shared__ float4 q4s[RNN_DIM / 4];   // 4 KB
    __shared__ float red[4][64];
    const int b = blockIdx.y;
    const int tid = threadIdx.x;          // 256
    q4s[tid] = reinterpret_cast<const float4*>(query + (size_t)b * RNN_DIM)[tid];
    __syncthreads();
    const int al = tid & 63;
    const int rp = tid >> 6;                    // 0..3 : K-quarter
    const int a  = blockIdx.x * 64 + al;
    const float4* w4 = reinterpret_cast<const float4*>(Wq + (size_t)a * RNN_DIM) + rp * 64;
    float acc = 0.f;
    #pragma unroll 8
    for (int i = 0; i < 64; ++i) {
        float4 w = w4[i];
        float4 q = q4s[rp * 64 + i];
        acc += w.x * q.x + w.y * q.y + w.z * q.z + w.w * q.w;
    }
    red[rp][al] = acc;
    __syncthreads();
    if (tid < 64) {
        float r = red[0][tid] + red[1][tid] + red[2][tid] + red[3][tid];
        pq[b * ATT_DIM + blockIdx.x * 64 + tid] = r;
    }
}

// --- Kernel B (FUSED): conv + loc proj + tanh + v-dot + mask + exp + ctx --
// Same grid decomposition as the old k_energy/k_ctx_partial pair: one block
// per (b, 64-t tile). After the energy tail produces p = exp(e) for the
// tile (numerically safe unnormalized: |e| <= ||v||_1 ~ 5), the SAME block
// streams its 64x512 mem tile (128 KB) and accumulates the weighted
// partial context. Blocks in the BW-bound ctx phase overlap blocks in the
// VALU-bound energy phase -> sum compresses toward max() instead of sum().
__global__ __launch_bounds__(256) void k_fused(
    const float* __restrict__ att,   // [B,2,T]
    const float* __restrict__ pm,    // [B,T,128]
    const float* __restrict__ cw,    // [32,2,31]
    const float* __restrict__ Wl,    // [128,32]
    const float* __restrict__ v,     // [128]
    const float* __restrict__ pq,    // [B,128]
    const int*   __restrict__ mask,  // [B,T] (bool -> int32)
    const float* __restrict__ mem,   // [B,T,512]
    float* __restrict__ P,           // [B,T]  unnormalized exp(e)
    float* __restrict__ part)        // [B,64,512] half-tile partial contexts
{
    __shared__ float att_s[2][TT + KSIZE - 1];        // 2 x 94
    __shared__ float loc_s[N_FILT][TT];               // 32 x 64
    __shared__ float pm_s[TT * (ATT_DIM + 1)];        // 64 x 129 (pad->free banks)
    __shared__ float ep_s[4][TT];
    __shared__ float p_s[TT];

    const int b   = blockIdx.y;
    const int ts  = blockIdx.x;
    const int t0  = ts * TT;
    const int tid = threadIdx.x;
    const int lane = tid & 63;
    const int w    = __builtin_amdgcn_readfirstlane(tid >> 6);

    // stage conv input window (zero padded at edges)
    if (tid < 2 * (TT + KSIZE - 1)) {
        int c = tid / (TT + KSIZE - 1);
        int i = tid % (TT + KSIZE - 1);
        int gt = t0 + i - PAD_;
        att_s[c][i] = (gt >= 0 && gt < T_) ? att[(b * 2 + c) * T_ + gt] : 0.f;
    }
    // stage pm tile: float4 global loads, scalar LDS writes keep +1 pad
    {
        const float4* src4 = reinterpret_cast<const float4*>(
            pm + ((size_t)b * T_ + t0) * ATT_DIM);
        #pragma unroll
        for (int j = 0; j < TT * ATT_DIM / 4 / 256; ++j) {   // 8
            int idx = tid + 256 * j;          // float4 index
            int row = idx >> 5;               // 32 float4 per row
            int c4  = idx & 31;
            float4 vv = src4[idx];
            float* dst = pm_s + row * (ATT_DIM + 1) + c4 * 4;
            dst[0] = vv.x; dst[1] = vv.y; dst[2] = vv.z; dst[3] = vv.w;
        }
    }
    __syncthreads();

    // conv: wave w computes f in [8w, 8w+8), 4-way f-blocking so each
    // att_s read feeds 4 FMAs; conv weights are wave-uniform -> s_load
    #pragma unroll
    for (int p = 0; p < 2; ++p) {
        int fb = __builtin_amdgcn_readfirstlane(w * 8 + p * 4);
        float a0 = 0.f, a1 = 0.f, a2 = 0.f, a3 = 0.f;
        #pragma unroll
        for (int c = 0; c < 2; ++c) {
            #pragma unroll
            for (int k = 0; k < KSIZE; ++k) {
                float av = att_s[c][lane + k];
                a0 += av * cw[((fb + 0) * 2 + c) * KSIZE + k];
                a1 += av * cw[((fb + 1) * 2 + c) * KSIZE + k];
                a2 += av * cw[((fb + 2) * 2 + c) * KSIZE + k];
                a3 += av * cw[((fb + 3) * 2 + c) * KSIZE + k];
            }
        }
        loc_s[fb + 0][lane] = a0;
        loc_s[fb + 1][lane] = a1;
        loc_s[fb + 2][lane] = a2;
        loc_s[fb + 3][lane] = a3;
    }
    __syncthreads();

    // stage 2: lane = t, loc row in registers; wave w covers a in [32w,32w+32)
    float lreg[N_FILT];
    #pragma unroll
    for (int f = 0; f < N_FILT; ++f) lreg[f] = loc_s[f][lane];

    const float* pm_row = pm_s + lane * (ATT_DIM + 1);
    const float* pq_row = pq + b * ATT_DIM;
    float eacc = 0.f;
    const int abase = __builtin_amdgcn_readfirstlane(w * 32);
    #pragma unroll 2
    for (int j = 0; j < 32; ++j) {
        int a = abase + j;
        const float* wl_row = Wl + a * N_FILT;   // uniform -> s_load
        float pl = 0.f;
        #pragma unroll
        for (int f = 0; f < N_FILT; ++f)
            pl += wl_row[f] * lreg[f];
        float x = pl + pm_row[a] + pq_row[a];
        eacc += fast_tanh(x) * v[a];
    }
    ep_s[w][lane] = eacc;
    __syncthreads();

    // tail: mask + unnormalized exp -> global P and LDS broadcast
    if (tid < TT) {
        float e = ep_s[0][tid] + ep_s[1][tid] + ep_s[2][tid] + ep_s[3][tid];
        int t = t0 + tid;
        float p = (mask[b * T_ + t] != 0) ? 0.f : __expf(e);
        P[b * T_ + t] = p;
        p_s[tid] = p;
    }
    __syncthreads();

    // ctx phase: two 32-t halves (g = tid>>7), float4 per thread over d.
    const int g  = tid >> 7;          // 0..1 : which half of the tile
    const int d4 = tid & 127;         // float4 column
    const float4* m4 = reinterpret_cast<const float4*>(mem)
                     + ((size_t)b * T_ + t0 + g * 32) * (EMB_DIM / 4);
    float4 acc = make_float4(0.f, 0.f, 0.f, 0.f);
    #pragma unroll 8
    for (int i = 0; i < 32; ++i) {
        float wt = p_s[g * 32 + i];                    // LDS broadcast
        float4 mv = m4[(size_t)i * (EMB_DIM / 4) + d4];
        acc.x += wt * mv.x; acc.y += wt * mv.y;
        acc.z += wt * mv.z; acc.w += wt * mv.w;
    }
    reinterpret_cast<float4*>(part)[
        ((size_t)(b * NPART + ts * 2 + g)) * (EMB_DIM / 4) + d4] = acc;
}

// ---- Kernel C: global normalize (weights in-place) + scaled ctx reduce ---
__global__ __launch_bounds__(256) void k_combine(
    const float* __restrict__ part,  // [B,64,512]
    float* __restrict__ W,           // [B,T] in: p, out: softmax weights
    float* __restrict__ ctx)         // [B,512]
{
    __shared__ float red[4];
    const int b = blockIdx.x, tid = threadIdx.x;
    float p[T_ / 256];                       // 8
    float s = 0.f;
    #pragma unroll
    for (int j = 0; j < T_ / 256; ++j) {
        p[j] = W[b * T_ + tid + 256 * j];
        s += p[j];
    }
    #pragma unroll
    for (int off = 32; off >= 1; off >>= 1)
        s += __shfl_xor(s, off, 64);
    if ((tid & 63) == 0) red[tid >> 6] = s;
    __syncthreads();
    const float S = red[0] + red[1] + red[2] + red[3];
    const float inv = 1.0f / S;
    #pragma unroll
    for (int j = 0; j < T_ / 256; ++j)
        W[b * T_ + tid + 256 * j] = p[j] * inv;
    #pragma unroll
    for (int j = 0; j < EMB_DIM / 256; ++j) {    // 2
        int d = tid + 256 * j;
        float acc = 0.f;
        #pragma unroll
        for (int sl = 0; sl < NPART; ++sl)
            acc += part[((size_t)b * NPART + sl) * EMB_DIM + d];
        ctx[b * EMB_DIM + d] = acc * inv;
    }
}

extern "C" void kernel_launch(void* const* d_in, const int* in_sizes, int n_in,
                              void* d_out, int out_size, void* d_ws, size_t ws_size,
                              hipStream_t stream) {
    const float* query = (const float*)d_in[0];
    const float* pm    = (const float*)d_in[1];
    const float* att   = (const float*)d_in[2];
    const int*   mask  = (const int*)d_in[3];
    const float* mem   = (const float*)d_in[4];
    const float* Wq    = (const float*)d_in[5];
    const float* cw    = (const float*)d_in[6];
    const float* Wl    = (const float*)d_in[7];
    const float* vw    = (const float*)d_in[8];

    float* ctx = (float*)d_out;                  // [64,512]   output 0
    float* wts = (float*)d_out + B_ * EMB_DIM;   // [64,2048]  output 1 (p -> w in place)
    float* pq   = (float*)d_ws;                  // 8192 floats
    float* part = pq + B_ * ATT_DIM;             // 64*64*512 floats (8 MB)

    k_pq     <<<dim3(2, B_),        dim3(256), 0, stream>>>(query, Wq, pq);
    k_fused  <<<dim3(NSLICE, B_),   dim3(256), 0, stream>>>(att, pm, cw, Wl, vw, pq, mask, mem, wts, part);
    k_combine<<<dim3(B_),           dim3(256), 0, stream>>>(part, wts, ctx);
}

// Round 4
// 437.674 us; speedup vs baseline: 1.0420x; 1.0420x over previous
//
#include <hip/hip_runtime.h>
#include <math.h>

#define B_ 64
#define T_ 2048
#define RNN_DIM 1024
#define EMB_DIM 512
#define ATT_DIM 128
#define N_FILT 32
#define KSIZE 31
#define PAD_ 15
#define TT 64           // t-tile for the fused kernel
#define NSLICE 32       // t-tiles per row
#define NPART 64        // 2 half-tile partials per tile

__device__ __forceinline__ float fast_tanh(float x) {
    // 1 - 2/(e^{2x}+1); exact at +-inf saturation, ~1e-7 abs err
    float e = __expf(2.0f * x);
    return 1.0f - 2.0f / (e + 1.0f);
}

// ---------------- Kernel A: pq[b,a] = sum_r query[b,r] * Wq[a,r] ----------
__global__ __launch_bounds__(256) void k_pq(const float* __restrict__ query,
                                            const float* __restrict__ Wq,
                                            float* __restrict__ pq) {
    __shared__ float4 q4s[RNN_DIM / 4];   // 4 KB
    __shared__ float red[4][64];
    const int b = blockIdx.y;
    const int tid = threadIdx.x;          // 256
    q4s[tid] = reinterpret_cast<const float4*>(query + (size_t)b * RNN_DIM)[tid];
    __syncthreads();
    const int al = tid & 63;
    const int rp = tid >> 6;                    // 0..3 : K-quarter
    const int a  = blockIdx.x * 64 + al;
    const float4* w4 = reinterpret_cast<const float4*>(Wq + (size_t)a * RNN_DIM) + rp * 64;
    float acc = 0.f;
    #pragma unroll 8
    for (int i = 0; i < 64; ++i) {
        float4 w = w4[i];
        float4 q = q4s[rp * 64 + i];
        acc += w.x * q.x + w.y * q.y + w.z * q.z + w.w * q.w;
    }
    red[rp][al] = acc;
    __syncthreads();
    if (tid < 64) {
        float r = red[0][tid] + red[1][tid] + red[2][tid] + red[3][tid];
        pq[b * ATT_DIM + blockIdx.x * 64 + tid] = r;
    }
}

// --- Kernel B (FUSED): conv + loc proj + tanh + v-dot + mask + exp + ctx --
// MASK-SKIP version: ~50% of t-rows are masked (p == 0 exactly). Those rows
// contribute nothing, so we (a) never stage their pm row (garbage LDS flows
// only into lanes whose p is forced to 0 -> discarded), and (b) skip their
// 2 KB mem row in the ctx phase (wt is wave-uniform -> execz branch; even
// predicated, VMEM with exec=0 fetches nothing). Bit-exact vs full reads.
__global__ __launch_bounds__(256) void k_fused(
    const float* __restrict__ att,   // [B,2,T]
    const float* __restrict__ pm,    // [B,T,128]
    const float* __restrict__ cw,    // [32,2,31]
    const float* __restrict__ Wl,    // [128,32]
    const float* __restrict__ v,     // [128]
    const float* __restrict__ pq,    // [B,128]
    const int*   __restrict__ mask,  // [B,T] (bool -> int32)
    const float* __restrict__ mem,   // [B,T,512]
    float* __restrict__ P,           // [B,T]  unnormalized exp(e)
    float* __restrict__ part)        // [B,64,512] half-tile partial contexts
{
    __shared__ float att_s[2][TT + KSIZE - 1];        // 2 x 94
    __shared__ float loc_s[N_FILT][TT];               // 32 x 64
    __shared__ float pm_s[TT * (ATT_DIM + 1)];        // 64 x 129 (pad->free banks)
    __shared__ float ep_s[4][TT];
    __shared__ float p_s[TT];
    __shared__ int   msk_s[TT];

    const int b   = blockIdx.y;
    const int ts  = blockIdx.x;
    const int t0  = ts * TT;
    const int tid = threadIdx.x;
    const int lane = tid & 63;
    const int w    = __builtin_amdgcn_readfirstlane(tid >> 6);

    // stage the tile's mask row (drives pm-skip + ctx-skip + tail)
    if (tid < TT) msk_s[tid] = mask[b * T_ + t0 + tid];
    // stage conv input window (zero padded at edges)
    if (tid < 2 * (TT + KSIZE - 1)) {
        int c = tid / (TT + KSIZE - 1);
        int i = tid % (TT + KSIZE - 1);
        int gt = t0 + i - PAD_;
        att_s[c][i] = (gt >= 0 && gt < T_) ? att[(b * 2 + c) * T_ + gt] : 0.f;
    }
    __syncthreads();   // msk_s ready

    // stage pm tile, skipping masked rows (~50% of the 32 KB)
    {
        const float4* src4 = reinterpret_cast<const float4*>(
            pm + ((size_t)b * T_ + t0) * ATT_DIM);
        #pragma unroll
        for (int j = 0; j < TT * ATT_DIM / 4 / 256; ++j) {   // 8
            int idx = tid + 256 * j;          // float4 index
            int row = idx >> 5;               // 32 float4 per row
            if (msk_s[row] == 0) {
                int c4  = idx & 31;
                float4 vv = src4[idx];
                float* dst = pm_s + row * (ATT_DIM + 1) + c4 * 4;
                dst[0] = vv.x; dst[1] = vv.y; dst[2] = vv.z; dst[3] = vv.w;
            }
        }
    }
    __syncthreads();

    // conv: wave w computes f in [8w, 8w+8), 4-way f-blocking so each
    // att_s read feeds 4 FMAs; conv weights are wave-uniform -> s_load
    #pragma unroll
    for (int p = 0; p < 2; ++p) {
        int fb = __builtin_amdgcn_readfirstlane(w * 8 + p * 4);
        float a0 = 0.f, a1 = 0.f, a2 = 0.f, a3 = 0.f;
        #pragma unroll
        for (int c = 0; c < 2; ++c) {
            #pragma unroll
            for (int k = 0; k < KSIZE; ++k) {
                float av = att_s[c][lane + k];
                a0 += av * cw[((fb + 0) * 2 + c) * KSIZE + k];
                a1 += av * cw[((fb + 1) * 2 + c) * KSIZE + k];
                a2 += av * cw[((fb + 2) * 2 + c) * KSIZE + k];
                a3 += av * cw[((fb + 3) * 2 + c) * KSIZE + k];
            }
        }
        loc_s[fb + 0][lane] = a0;
        loc_s[fb + 1][lane] = a1;
        loc_s[fb + 2][lane] = a2;
        loc_s[fb + 3][lane] = a3;
    }
    __syncthreads();

    // stage 2: lane = t, loc row in registers; wave w covers a in [32w,32w+32)
    float lreg[N_FILT];
    #pragma unroll
    for (int f = 0; f < N_FILT; ++f) lreg[f] = loc_s[f][lane];

    const float* pm_row = pm_s + lane * (ATT_DIM + 1);
    const float* pq_row = pq + b * ATT_DIM;
    float eacc = 0.f;
    const int abase = __builtin_amdgcn_readfirstlane(w * 32);
    #pragma unroll 2
    for (int j = 0; j < 32; ++j) {
        int a = abase + j;
        const float* wl_row = Wl + a * N_FILT;   // uniform -> s_load
        float pl = 0.f;
        #pragma unroll
        for (int f = 0; f < N_FILT; ++f)
            pl += wl_row[f] * lreg[f];
        float x = pl + pm_row[a] + pq_row[a];
        eacc += fast_tanh(x) * v[a];
    }
    ep_s[w][lane] = eacc;
    __syncthreads();

    // tail: mask + unnormalized exp -> global P and LDS broadcast
    // (|e| <= ||v||_1 ~ 5, so exp never overflows; garbage eacc from
    // unstaged pm rows only reaches masked lanes -> forced to 0 here)
    if (tid < TT) {
        float e = ep_s[0][tid] + ep_s[1][tid] + ep_s[2][tid] + ep_s[3][tid];
        float p = (msk_s[tid] != 0) ? 0.f : __expf(e);
        P[b * T_ + t0 + tid] = p;
        p_s[tid] = p;
    }
    __syncthreads();

    // ctx phase: two 32-t halves (g = tid>>7), float4 per thread over d.
    // wt is wave-uniform -> masked rows skip their 2 KB mem read entirely.
    const int g  = tid >> 7;          // 0..1 : which half of the tile
    const int d4 = tid & 127;         // float4 column
    const float4* m4 = reinterpret_cast<const float4*>(mem)
                     + ((size_t)b * T_ + t0 + g * 32) * (EMB_DIM / 4);
    float4 acc = make_float4(0.f, 0.f, 0.f, 0.f);
    #pragma unroll 4
    for (int i = 0; i < 32; ++i) {
        float wt = p_s[g * 32 + i];                    // LDS broadcast, uniform
        if (wt != 0.f) {
            float4 mv = m4[(size_t)i * (EMB_DIM / 4) + d4];
            acc.x += wt * mv.x; acc.y += wt * mv.y;
            acc.z += wt * mv.z; acc.w += wt * mv.w;
        }
    }
    reinterpret_cast<float4*>(part)[
        ((size_t)(b * NPART + ts * 2 + g)) * (EMB_DIM / 4) + d4] = acc;
}

// ---- Kernel C: global normalize (weights in-place) + scaled ctx reduce ---
__global__ __launch_bounds__(256) void k_combine(
    const float* __restrict__ part,  // [B,64,512]
    float* __restrict__ W,           // [B,T] in: p, out: softmax weights
    float* __restrict__ ctx)         // [B,512]
{
    __shared__ float red[4];
    const int b = blockIdx.x, tid = threadIdx.x;
    float p[T_ / 256];                       // 8
    float s = 0.f;
    #pragma unroll
    for (int j = 0; j < T_ / 256; ++j) {
        p[j] = W[b * T_ + tid + 256 * j];
        s += p[j];
    }
    #pragma unroll
    for (int off = 32; off >= 1; off >>= 1)
        s += __shfl_xor(s, off, 64);
    if ((tid & 63) == 0) red[tid >> 6] = s;
    __syncthreads();
    const float S = red[0] + red[1] + red[2] + red[3];
    const float inv = 1.0f / S;
    #pragma unroll
    for (int j = 0; j < T_ / 256; ++j)
        W[b * T_ + tid + 256 * j] = p[j] * inv;
    #pragma unroll
    for (int j = 0; j < EMB_DIM / 256; ++j) {    // 2
        int d = tid + 256 * j;
        float acc = 0.f;
        #pragma unroll
        for (int sl = 0; sl < NPART; ++sl)
            acc += part[((size_t)b * NPART + sl) * EMB_DIM + d];
        ctx[b * EMB_DIM + d] = acc * inv;
    }
}

extern "C" void kernel_launch(void* const* d_in, const int* in_sizes, int n_in,
                              void* d_out, int out_size, void* d_ws, size_t ws_size,
                              hipStream_t stream) {
    const float* query = (const float*)d_in[0];
    const float* pm    = (const float*)d_in[1];
    const float* att   = (const float*)d_in[2];
    const int*   mask  = (const int*)d_in[3];
    const float* mem   = (const float*)d_in[4];
    const float* Wq    = (const float*)d_in[5];
    const float* cw    = (const float*)d_in[6];
    const float* Wl    = (const float*)d_in[7];
    const float* vw    = (const float*)d_in[8];

    float* ctx = (float*)d_out;                  // [64,512]   output 0
    float* wts = (float*)d_out + B_ * EMB_DIM;   // [64,2048]  output 1 (p -> w in place)
    float* pq   = (float*)d_ws;                  // 8192 floats
    float* part = pq + B_ * ATT_DIM;             // 64*64*512 floats (8 MB)

    k_pq     <<<dim3(2, B_),        dim3(256), 0, stream>>>(query, Wq, pq);
    k_fused  <<<dim3(NSLICE, B_),   dim3(256), 0, stream>>>(att, pm, cw, Wl, vw, pq, mask, mem, wts, part);
    k_combine<<<dim3(B_),           dim3(256), 0, stream>>>(part, wts, ctx);
}